// Round 4
// baseline (33.143 us; speedup 1.0000x reference)
//
#include <hip/hip_runtime.h>
#include <math.h>
#include <stdint.h>

// Problem constants
#define NN 2
#define LL 2304          // 48*48
#define CC 384
#define KK 16
#define DINO_SHIFT 0.7f

// Tiling: 96x96 pair tiles over the (s<=l) triangle
#define NT 24                      // LL / 96
#define TB 96
#define TT ((NT * (NT + 1)) / 2)   // 300 tiles per batch
#define NBLK2 (NN * TT)            // 600 blocks (600 % 8 == 0 -> bijective XCD swizzle)

typedef __attribute__((ext_vector_type(8))) short short8;   // 8 bf16
typedef __attribute__((ext_vector_type(4))) float f32x4;
typedef __attribute__((ext_vector_type(2))) float f32x2;

#define AS_G __attribute__((address_space(1)))
#define AS_L __attribute__((address_space(3)))

__device__ __forceinline__ unsigned short f2bf(float x) {
    union { float f; uint32_t u; } v; v.f = x;
    uint32_t r = v.u + 0x7fffu + ((v.u >> 16) & 1u);   // RNE
    return (unsigned short)(r >> 16);
}
__device__ __forceinline__ unsigned int pk2(float a, float b) {
    return (unsigned int)f2bf(a) | ((unsigned int)f2bf(b) << 16);
}

__device__ __forceinline__ void gll16(const void* g, void* l) {
    // async global->LDS, 16B per lane; LDS dest = wave-uniform base + lane*16
    __builtin_amdgcn_global_load_lds((const AS_G unsigned int*)g,
                                     (AS_L unsigned int*)l, 16, 0, 0);
}

// ---------------------------------------------------------------------------
// Kernel 1: per row r: fnorm = bf16(f_r / max(||f_r||,eps)) (packed dword
// stores); Ppad/ppad = bf16 exp(p)/p padded to 32; selfdot = sum P*p.
// Also zeroes the last-block counter (block 0).
// ---------------------------------------------------------------------------
__global__ void prep_kernel(const float* __restrict__ f, const float* __restrict__ p,
                            unsigned short* __restrict__ fnorm,
                            unsigned short* __restrict__ Ppad,
                            unsigned short* __restrict__ ppad,
                            float* __restrict__ selfdot,
                            unsigned int* __restrict__ counter) {
    if (blockIdx.x == 0 && threadIdx.x == 0) counter[0] = 0u;
    const int r = blockIdx.x * 4 + (threadIdx.x >> 6);
    const int lane = threadIdx.x & 63;
    const f32x2* frow2 = (const f32x2*)(f + (size_t)r * CC);
    f32x2 v[3];
    float ss = 0.f;
#pragma unroll
    for (int k = 0; k < 3; ++k) {
        v[k] = frow2[lane + 64 * k];
        ss = fmaf(v[k][0], v[k][0], fmaf(v[k][1], v[k][1], ss));
    }
#pragma unroll
    for (int off = 32; off; off >>= 1) ss += __shfl_xor(ss, off);
    const float rn = 1.0f / fmaxf(sqrtf(ss), 1e-12f);
    unsigned int* fnr32 = (unsigned int*)(fnorm + (size_t)r * CC);
#pragma unroll
    for (int k = 0; k < 3; ++k)
        fnr32[lane + 64 * k] = pk2(v[k][0] * rn, v[k][1] * rn);

    if (lane < 32) {
        float pv = 0.f, e = 0.f;
        if (lane < KK) { pv = p[(size_t)r * KK + lane]; e = expf(pv); }
        Ppad[(size_t)r * 32 + lane] = (lane < KK) ? f2bf(e)  : (unsigned short)0;
        ppad[(size_t)r * 32 + lane] = (lane < KK) ? f2bf(pv) : (unsigned short)0;
        float sd = e * pv;
#pragma unroll
        for (int off = 8; off; off >>= 1) sd += __shfl_xor(sd, off, 16);
        if (lane == 0) selfdot[r] = sd;
    }
}

// ---------------------------------------------------------------------------
// Kernel 2: 96x96 triangular pair tile (weight 2 off-diagonal), 4 waves 2x2,
// per-wave 48x48 = 3x3 frags of mfma_f32_16x16x32_bf16.
// global_load_lds staging (pre-swizzled source -> linear LDS -> swizzled read),
// 2-phase double buffer. Last K-iter prefetches the epilogue P/p tiles into
// the idle buffer. Last block (atomic counter) does the final reduce.
// ---------------------------------------------------------------------------
__global__ __launch_bounds__(256, 2) void pair_kernel(
    const unsigned short* __restrict__ fnorm,
    const unsigned short* __restrict__ Ppad, const unsigned short* __restrict__ ppad,
    const float* __restrict__ selfdot, float* __restrict__ partials,
    unsigned int* __restrict__ counter,
    const float* __restrict__ pw, const float* __restrict__ nw,
    float* __restrict__ out)
{
    __shared__ char lds[49152] __attribute__((aligned(16)));  // [2 buf][2 side][12KB]
    __shared__ float red[4][4];
    __shared__ unsigned int isLast;

    // XCD-aware swizzle (bijective: 600 = 8 * 75)
    const int b = (blockIdx.x & 7) * (NBLK2 / 8) + (blockIdx.x >> 3);
    const int n = b / TT;
    int t = b % TT;
    int i = 0;
    while (t >= NT - i) { t -= NT - i; ++i; }
    const int j = i + t;
    const int s0 = i * TB, l0 = j * TB;
    const bool diag = (i == j);
    const float wgt = diag ? 1.f : 2.f;

    const int tid = threadIdx.x, lane = tid & 63, w = tid >> 6;
    const int wrow = w >> 1, wcol = w & 1;

    const unsigned short* fn = fnorm + (size_t)n * LL * CC;
    const int srow8 = lane >> 3, sch = lane & 7;   // f-staging geometry

    f32x4 acc[3][3] = {};

    auto stageF = [&](int buf, int c0) {
        char* base = lds + buf * 24576;
#pragma unroll
        for (int q = 0; q < 3; ++q) {
            const int r0 = w * 24 + q * 8;
            const int row = r0 + srow8;
            const char* src = (const char*)(fn + (size_t)(s0 + row) * CC) + c0 * 2
                              + ((sch ^ (row & 7)) << 4);
            gll16(src, base + r0 * 128);
        }
        if (!diag) {
#pragma unroll
            for (int q = 0; q < 3; ++q) {
                const int r0 = w * 24 + q * 8;
                const int row = r0 + srow8;
                const char* src = (const char*)(fn + (size_t)(l0 + row) * CC) + c0 * 2
                                  + ((sch ^ (row & 7)) << 4);
                gll16(src, base + 12288 + r0 * 128);
            }
        }
    };
    auto stagePP = [&]() {   // into buf0: P at [0,6K), p at [6144,12288)
        const char* Pb = (const char*)Ppad + (size_t)(n * LL + s0) * 64;
        const char* pb = (const char*)ppad + (size_t)(n * LL + l0) * 64;
        const int erow = lane >> 2, ech = lane & 3;
#pragma unroll
        for (int q3 = 0; q3 < 3; ++q3) {
            const int q = w * 3 + q3;                 // 0..11, wave-uniform
            const int qq = (q < 6) ? q : q - 6;
            const int row = qq * 16 + erow;
            const char* sb = (q < 6) ? Pb : pb;
            gll16(sb + row * 64 + ((ech ^ (row & 3)) << 4),
                  lds + ((q < 6) ? 0 : 6144) + qq * 1024);
        }
    };

    stageF(0, 0);
    asm volatile("s_waitcnt vmcnt(0)" ::: "memory");
    __syncthreads();

#pragma unroll
    for (int tt = 0; tt < 6; ++tt) {
        if (tt < 5) stageF((tt + 1) & 1, (tt + 1) * 64);   // async prefetch
        else        stagePP();                             // epilogue prefetch into buf0
        const char* abase = lds + (tt & 1) * 24576;
        const char* bbase = diag ? abase : abase + 12288;
#pragma unroll
        for (int ks = 0; ks < 2; ++ks) {
            short8 a[3], bb[3];
#pragma unroll
            for (int im = 0; im < 3; ++im) {
                const int row = wrow * 48 + im * 16 + (lane & 15);
                a[im] = *(const short8*)(abase + row * 128
                         + (((ks * 4 + (lane >> 4)) ^ (row & 7)) << 4));
            }
#pragma unroll
            for (int jn = 0; jn < 3; ++jn) {
                const int row = wcol * 48 + jn * 16 + (lane & 15);
                bb[jn] = *(const short8*)(bbase + row * 128
                         + (((ks * 4 + (lane >> 4)) ^ (row & 7)) << 4));
            }
#pragma unroll
            for (int im = 0; im < 3; ++im)
#pragma unroll
                for (int jn = 0; jn < 3; ++jn)
                    acc[im][jn] = __builtin_amdgcn_mfma_f32_16x16x32_bf16(
                        a[im], bb[jn], acc[im][jn], 0, 0, 0);
        }
        asm volatile("s_waitcnt vmcnt(0)" ::: "memory");
        __syncthreads();
    }

    // ---- epilogue: P tile at lds[0,6K), p tile at lds[6144,12288) (already staged)
    short8 a2[3], b2[3];
#pragma unroll
    for (int im = 0; im < 3; ++im) {
        const int row = wrow * 48 + im * 16 + (lane & 15);
        a2[im] = *(const short8*)(lds + row * 64 + (((lane >> 4) ^ (row & 3)) << 4));
    }
#pragma unroll
    for (int jn = 0; jn < 3; ++jn) {
        const int row = wcol * 48 + jn * 16 + (lane & 15);
        b2[jn] = *(const short8*)(lds + 6144 + row * 64 + (((lane >> 4) ^ (row & 3)) << 4));
    }

    float pos = 0.f, neg = 0.f, npc = 0.f, nnc = 0.f;
#pragma unroll
    for (int im = 0; im < 3; ++im) {
        const f32x4 sd4 = *(const f32x4*)(selfdot + (size_t)n * LL + s0
                            + wrow * 48 + im * 16 + ((lane >> 4) << 2));
#pragma unroll
        for (int jn = 0; jn < 3; ++jn) {
            f32x4 z = {0.f, 0.f, 0.f, 0.f};
            f32x4 pdv = __builtin_amdgcn_mfma_f32_16x16x32_bf16(a2[im], b2[jn], z, 0, 0, 0);
#pragma unroll
            for (int r = 0; r < 4; ++r) {
                const float fc = acc[im][jn][r] - DINO_SHIFT;
                const float pc = sd4[r] - pdv[r];
                const float v = fc * pc;
                if (fc > 0.f)      { pos += v; npc += 1.f; }
                else if (fc < 0.f) { neg += v; nnc += 1.f; }
            }
        }
    }
    pos *= wgt; neg *= wgt; npc *= wgt; nnc *= wgt;

#pragma unroll
    for (int off = 32; off; off >>= 1) {
        pos += __shfl_xor(pos, off); neg += __shfl_xor(neg, off);
        npc += __shfl_xor(npc, off); nnc += __shfl_xor(nnc, off);
    }
    if (lane == 0) { red[w][0] = pos; red[w][1] = neg; red[w][2] = npc; red[w][3] = nnc; }
    __syncthreads();
    if (tid == 0) {
        partials[b * 4 + 0] = red[0][0] + red[1][0] + red[2][0] + red[3][0];
        partials[b * 4 + 1] = red[0][1] + red[1][1] + red[2][1] + red[3][1];
        partials[b * 4 + 2] = red[0][2] + red[1][2] + red[2][2] + red[3][2];
        partials[b * 4 + 3] = red[0][3] + red[1][3] + red[2][3] + red[3][3];
        __threadfence();                         // release partials (device scope)
        unsigned int r = atomicAdd(counter, 1u);
        isLast = (r == NBLK2 - 1) ? 1u : 0u;
    }
    __syncthreads();

    if (isLast && tid < 64) {
        __threadfence();                         // acquire side
        float ps = 0.f, ng = 0.f, np = 0.f, nn = 0.f;
        for (int q = tid; q < NBLK2; q += 64) {
            const f32x4 v = *(const f32x4*)(partials + q * 4);
            ps += v[0]; ng += v[1]; np += v[2]; nn += v[3];
        }
#pragma unroll
        for (int off = 32; off; off >>= 1) {
            ps += __shfl_xor(ps, off); ng += __shfl_xor(ng, off);
            np += __shfl_xor(np, off); nn += __shfl_xor(nn, off);
        }
        if (tid == 0) out[0] = (ps / np) * pw[0] + (ng / nn) * nw[0];
    }
}

extern "C" void kernel_launch(void* const* d_in, const int* in_sizes, int n_in,
                              void* d_out, int out_size, void* d_ws, size_t ws_size,
                              hipStream_t stream) {
    const float* f  = (const float*)d_in[0];
    const float* p  = (const float*)d_in[1];
    const float* pw = (const float*)d_in[2];
    const float* nw = (const float*)d_in[3];
    float* out = (float*)d_out;

    // ws layout (16B-aligned): fnorm | Ppad | ppad | selfdot | partials | counter
    unsigned short* fnorm = (unsigned short*)d_ws;                        // N*L*C bf16
    unsigned short* Ppad  = fnorm + (size_t)NN * LL * CC;                 // N*L*32
    unsigned short* ppad  = Ppad + (size_t)NN * LL * 32;                  // N*L*32
    float* selfdot  = (float*)(ppad + (size_t)NN * LL * 32);              // N*L
    float* partials = selfdot + (size_t)NN * LL;                          // NBLK2*4
    unsigned int* counter = (unsigned int*)(partials + (size_t)NBLK2 * 4);

    prep_kernel<<<(NN * LL) / 4, 256, 0, stream>>>(f, p, fnorm, Ppad, ppad, selfdot, counter);
    pair_kernel<<<NBLK2, 256, 0, stream>>>(fnorm, Ppad, ppad, selfdot, partials,
                                           counter, pw, nw, out);
}

// Round 5
// 29.480 us; speedup vs baseline: 1.1243x; 1.1243x over previous
//
#include <hip/hip_runtime.h>
#include <math.h>
#include <stdint.h>

// Problem constants
#define NN 2
#define LL 2304          // 48*48
#define CC 384
#define KK 16
#define DINO_SHIFT 0.7f

// Tiling: 96x96 pair tiles over the (s<=l) triangle
#define NT 24                      // LL / 96
#define TB 96
#define TT ((NT * (NT + 1)) / 2)   // 300 tiles per batch
#define NBLK2 (NN * TT)            // 600 blocks

typedef __attribute__((ext_vector_type(8))) short short8;   // 8 bf16
typedef __attribute__((ext_vector_type(4))) float f32x4;
typedef __attribute__((ext_vector_type(2))) float f32x2;

#define AS_G __attribute__((address_space(1)))
#define AS_L __attribute__((address_space(3)))

__device__ __forceinline__ unsigned short f2bf(float x) {
    union { float f; uint32_t u; } v; v.f = x;
    uint32_t r = v.u + 0x7fffu + ((v.u >> 16) & 1u);   // RNE
    return (unsigned short)(r >> 16);
}
__device__ __forceinline__ unsigned int pk2(float a, float b) {
    return (unsigned int)f2bf(a) | ((unsigned int)f2bf(b) << 16);
}

__device__ __forceinline__ void gll16(const void* g, void* l) {
    // async global->LDS, 16B per lane; LDS dest = wave-uniform base + lane*16
    __builtin_amdgcn_global_load_lds((const AS_G unsigned int*)g,
                                     (AS_L unsigned int*)l, 16, 0, 0);
}

// ---------------------------------------------------------------------------
// Kernel 1: per row r: fnorm = bf16(f_r / max(||f_r||,eps)) (packed dword
// stores); Ppad/ppad = bf16 exp(p)/p padded to 32; selfdot = sum P*p.
// ---------------------------------------------------------------------------
__global__ void prep_kernel(const float* __restrict__ f, const float* __restrict__ p,
                            unsigned short* __restrict__ fnorm,
                            unsigned short* __restrict__ Ppad,
                            unsigned short* __restrict__ ppad,
                            float* __restrict__ selfdot) {
    const int r = blockIdx.x * 4 + (threadIdx.x >> 6);
    const int lane = threadIdx.x & 63;
    const f32x2* frow2 = (const f32x2*)(f + (size_t)r * CC);
    f32x2 v[3];
    float ss = 0.f;
#pragma unroll
    for (int k = 0; k < 3; ++k) {
        v[k] = frow2[lane + 64 * k];
        ss = fmaf(v[k][0], v[k][0], fmaf(v[k][1], v[k][1], ss));
    }
#pragma unroll
    for (int off = 32; off; off >>= 1) ss += __shfl_xor(ss, off);
    const float rn = 1.0f / fmaxf(sqrtf(ss), 1e-12f);
    unsigned int* fnr32 = (unsigned int*)(fnorm + (size_t)r * CC);
#pragma unroll
    for (int k = 0; k < 3; ++k)
        fnr32[lane + 64 * k] = pk2(v[k][0] * rn, v[k][1] * rn);

    if (lane < 32) {
        float pv = 0.f, e = 0.f;
        if (lane < KK) { pv = p[(size_t)r * KK + lane]; e = expf(pv); }
        Ppad[(size_t)r * 32 + lane] = (lane < KK) ? f2bf(e)  : (unsigned short)0;
        ppad[(size_t)r * 32 + lane] = (lane < KK) ? f2bf(pv) : (unsigned short)0;
        float sd = e * pv;
#pragma unroll
        for (int off = 8; off; off >>= 1) sd += __shfl_xor(sd, off, 16);
        if (lane == 0) selfdot[r] = sd;
    }
}

// ---------------------------------------------------------------------------
// Kernel 2: 96x96 triangular pair tile (weight 2 off-diagonal), 4 waves 2x2,
// per-wave 48x48 = 3x3 frags of mfma_f32_16x16x32_bf16.
// 3-buffer, 2-deep counted-vmcnt pipeline (T3+T4): raw s_barrier, never
// vmcnt(0) in the main loop. Diagonal tiles stage both sides (uniform vmcnt).
// Epilogue P/p tiles prefetched in the iter-4 pipeline slot into buf0.
// ---------------------------------------------------------------------------
__global__ __launch_bounds__(256, 2) void pair_kernel(
    const unsigned short* __restrict__ fnorm,
    const unsigned short* __restrict__ Ppad, const unsigned short* __restrict__ ppad,
    const float* __restrict__ selfdot, float* __restrict__ partials)
{
    __shared__ char lds[73728] __attribute__((aligned(16)));  // 3 bufs x 24576
    __shared__ float red[4][4];

    const int b = blockIdx.x;
    const int n = b / TT;
    int t = b % TT;
    int i = 0;
    while (t >= NT - i) { t -= NT - i; ++i; }
    const int j = i + t;
    const int s0 = i * TB, l0 = j * TB;
    const float wgt = (i == j) ? 1.f : 2.f;

    const int tid = threadIdx.x, lane = tid & 63, w = tid >> 6;
    const int wrow = w >> 1, wcol = w & 1;

    const unsigned short* fn = fnorm + (size_t)n * LL * CC;
    const int srow8 = lane >> 3, sch = lane & 7;   // f-staging geometry

    f32x4 acc[3][3] = {};

    // stage K-tile kt (64 elems = 128B per row) of both panels into buffer buf
    auto stageF = [&](int buf, int kt) {
        char* base = lds + buf * 24576;
#pragma unroll
        for (int q = 0; q < 3; ++q) {
            const int r0 = w * 24 + q * 8;
            const int row = r0 + srow8;
            const int swz = (sch ^ (row & 7)) << 4;
            gll16((const char*)(fn + (size_t)(s0 + row) * CC) + kt * 128 + swz,
                  base + r0 * 128);
            gll16((const char*)(fn + (size_t)(l0 + row) * CC) + kt * 128 + swz,
                  base + 12288 + r0 * 128);
        }
    };
    auto stagePP = [&]() {   // into buf0: P at [0,6144), p at [6144,12288)
        const char* Pb = (const char*)Ppad + (size_t)(n * LL + s0) * 64;
        const char* pb = (const char*)ppad + (size_t)(n * LL + l0) * 64;
        const int erow = lane >> 2, ech = lane & 3;
#pragma unroll
        for (int q3 = 0; q3 < 3; ++q3) {
            const int q = w * 3 + q3;                 // 0..11, wave-uniform
            const int qq = (q < 6) ? q : q - 6;
            const int row = qq * 16 + erow;
            const char* sb = (q < 6) ? Pb : pb;
            gll16(sb + row * 64 + ((ech ^ (row & 3)) << 4),
                  lds + ((q < 6) ? 0 : 6144) + qq * 1024);
        }
    };
    auto compute = [&](int buf) {
        const char* abase = lds + buf * 24576;
        const char* bbase = abase + 12288;
#pragma unroll
        for (int ks = 0; ks < 2; ++ks) {
            short8 a[3], bb[3];
#pragma unroll
            for (int im = 0; im < 3; ++im) {
                const int row = wrow * 48 + im * 16 + (lane & 15);
                a[im] = *(const short8*)(abase + row * 128
                         + (((ks * 4 + (lane >> 4)) ^ (row & 7)) << 4));
            }
#pragma unroll
            for (int jn = 0; jn < 3; ++jn) {
                const int row = wcol * 48 + jn * 16 + (lane & 15);
                bb[jn] = *(const short8*)(bbase + row * 128
                         + (((ks * 4 + (lane >> 4)) ^ (row & 7)) << 4));
            }
#pragma unroll
            for (int im = 0; im < 3; ++im)
#pragma unroll
                for (int jn = 0; jn < 3; ++jn)
                    acc[im][jn] = __builtin_amdgcn_mfma_f32_16x16x32_bf16(
                        a[im], bb[jn], acc[im][jn], 0, 0, 0);
        }
    };

    // Pipeline: 2-deep prefetch, 12 loads/wave/stage, counted vmcnt.
    stageF(0, 0);
    stageF(1, 1);
#define K_ITER(TT_I, VMC) \
    { if (TT_I < 4) stageF((TT_I + 2) % 3, TT_I + 2); \
      else if (TT_I == 4) stagePP(); \
      asm volatile("s_waitcnt vmcnt(" #VMC ")" ::: "memory"); \
      asm volatile("s_barrier" ::: "memory"); \
      compute(TT_I % 3); \
      asm volatile("s_barrier" ::: "memory"); }
    K_ITER(0, 12)
    K_ITER(1, 12)
    K_ITER(2, 12)
    K_ITER(3, 12)
    K_ITER(4, 9)
    K_ITER(5, 3)
#undef K_ITER
    asm volatile("s_waitcnt vmcnt(0)" ::: "memory");   // PP tiles landed
    asm volatile("s_barrier" ::: "memory");

    // ---- epilogue: P tile at lds[0,6144), p tile at lds[6144,12288)
    short8 a2[3], b2[3];
#pragma unroll
    for (int im = 0; im < 3; ++im) {
        const int row = wrow * 48 + im * 16 + (lane & 15);
        a2[im] = *(const short8*)(lds + row * 64 + (((lane >> 4) ^ (row & 3)) << 4));
    }
#pragma unroll
    for (int jn = 0; jn < 3; ++jn) {
        const int row = wcol * 48 + jn * 16 + (lane & 15);
        b2[jn] = *(const short8*)(lds + 6144 + row * 64 + (((lane >> 4) ^ (row & 3)) << 4));
    }

    float pos = 0.f, neg = 0.f, npc = 0.f, nnc = 0.f;
#pragma unroll
    for (int im = 0; im < 3; ++im) {
        const f32x4 sd4 = *(const f32x4*)(selfdot + (size_t)n * LL + s0
                            + wrow * 48 + im * 16 + ((lane >> 4) << 2));
#pragma unroll
        for (int jn = 0; jn < 3; ++jn) {
            f32x4 z = {0.f, 0.f, 0.f, 0.f};
            f32x4 pdv = __builtin_amdgcn_mfma_f32_16x16x32_bf16(a2[im], b2[jn], z, 0, 0, 0);
#pragma unroll
            for (int r = 0; r < 4; ++r) {
                const float fc = acc[im][jn][r] - DINO_SHIFT;
                const float pc = sd4[r] - pdv[r];
                const float v = fc * pc;
                if (fc > 0.f)      { pos += v; npc += 1.f; }
                else if (fc < 0.f) { neg += v; nnc += 1.f; }
            }
        }
    }
    pos *= wgt; neg *= wgt; npc *= wgt; nnc *= wgt;

#pragma unroll
    for (int off = 32; off; off >>= 1) {
        pos += __shfl_xor(pos, off); neg += __shfl_xor(neg, off);
        npc += __shfl_xor(npc, off); nnc += __shfl_xor(nnc, off);
    }
    if (lane == 0) { red[w][0] = pos; red[w][1] = neg; red[w][2] = npc; red[w][3] = nnc; }
    __syncthreads();
    if (tid == 0) {
        partials[b * 4 + 0] = red[0][0] + red[1][0] + red[2][0] + red[3][0];
        partials[b * 4 + 1] = red[0][1] + red[1][1] + red[2][1] + red[3][1];
        partials[b * 4 + 2] = red[0][2] + red[1][2] + red[2][2] + red[3][2];
        partials[b * 4 + 3] = red[0][3] + red[1][3] + red[2][3] + red[3][3];
    }
}

// ---------------------------------------------------------------------------
// Kernel 3: deterministic final reduce
// ---------------------------------------------------------------------------
__global__ void final_kernel(const float* __restrict__ partials,
                             const float* __restrict__ pw,
                             const float* __restrict__ nw,
                             float* __restrict__ out) {
    __shared__ float red[4][4];
    const int tid = threadIdx.x;
    float pos = 0.f, neg = 0.f, np = 0.f, nn = 0.f;
    for (int i = tid; i < NBLK2; i += 256) {
        const f32x4 v = *(const f32x4*)(partials + i * 4);
        pos += v[0]; neg += v[1]; np += v[2]; nn += v[3];
    }
#pragma unroll
    for (int off = 32; off; off >>= 1) {
        pos += __shfl_xor(pos, off); neg += __shfl_xor(neg, off);
        np  += __shfl_xor(np, off);  nn  += __shfl_xor(nn, off);
    }
    const int w = tid >> 6, lane = tid & 63;
    if (lane == 0) { red[w][0] = pos; red[w][1] = neg; red[w][2] = np; red[w][3] = nn; }
    __syncthreads();
    if (tid == 0) {
        pos = red[0][0] + red[1][0] + red[2][0] + red[3][0];
        neg = red[0][1] + red[1][1] + red[2][1] + red[3][1];
        np  = red[0][2] + red[1][2] + red[2][2] + red[3][2];
        nn  = red[0][3] + red[1][3] + red[2][3] + red[3][3];
        out[0] = (pos / np) * pw[0] + (neg / nn) * nw[0];
    }
}

extern "C" void kernel_launch(void* const* d_in, const int* in_sizes, int n_in,
                              void* d_out, int out_size, void* d_ws, size_t ws_size,
                              hipStream_t stream) {
    const float* f  = (const float*)d_in[0];
    const float* p  = (const float*)d_in[1];
    const float* pw = (const float*)d_in[2];
    const float* nw = (const float*)d_in[3];
    float* out = (float*)d_out;

    // ws layout (16B-aligned): fnorm | Ppad | ppad | selfdot | partials
    unsigned short* fnorm = (unsigned short*)d_ws;                        // N*L*C bf16
    unsigned short* Ppad  = fnorm + (size_t)NN * LL * CC;                 // N*L*32
    unsigned short* ppad  = Ppad + (size_t)NN * LL * 32;                  // N*L*32
    float* selfdot  = (float*)(ppad + (size_t)NN * LL * 32);              // N*L
    float* partials = selfdot + (size_t)NN * LL;                          // NBLK2*4

    prep_kernel<<<(NN * LL) / 4, 256, 0, stream>>>(f, p, fnorm, Ppad, ppad, selfdot);
    pair_kernel<<<NBLK2, 256, 0, stream>>>(fnorm, Ppad, ppad, selfdot, partials);
    final_kernel<<<1, 256, 0, stream>>>(partials, pw, nw, out);
}

// Round 6
// 25.219 us; speedup vs baseline: 1.3142x; 1.1689x over previous
//
#include <hip/hip_runtime.h>
#include <math.h>
#include <stdint.h>

// Problem constants
#define NN 2
#define LL 2304          // 48*48
#define CC 384
#define KK 16
#define DINO_SHIFT 0.7f

// Tiling: 96x96 pair tiles over the (s<=l) triangle
#define NT 24                      // LL / 96
#define TB 96
#define TT ((NT * (NT + 1)) / 2)   // 300 tiles per batch
#define NBLK2 (NN * TT)            // 600 blocks

typedef __attribute__((ext_vector_type(8))) short short8;   // 8 bf16
typedef __attribute__((ext_vector_type(4))) float f32x4;
typedef __attribute__((ext_vector_type(2))) float f32x2;

#define AS_G __attribute__((address_space(1)))
#define AS_L __attribute__((address_space(3)))

__device__ __forceinline__ unsigned short f2bf(float x) {
    union { float f; uint32_t u; } v; v.f = x;
    uint32_t r = v.u + 0x7fffu + ((v.u >> 16) & 1u);   // RNE
    return (unsigned short)(r >> 16);
}
__device__ __forceinline__ unsigned int pk2(float a, float b) {
    return (unsigned int)f2bf(a) | ((unsigned int)f2bf(b) << 16);
}

__device__ __forceinline__ void gll16(const void* g, void* l) {
    // async global->LDS, 16B per lane; LDS dest = wave-uniform base + lane*16
    __builtin_amdgcn_global_load_lds((const AS_G unsigned int*)g,
                                     (AS_L unsigned int*)l, 16, 0, 0);
}

// ---------------------------------------------------------------------------
// Kernel 1: per row r: fnorm = bf16(f_r / max(||f_r||,eps)) (packed dword
// stores); Ppad/ppad = bf16 exp(p)/p padded to 32; selfdot = sum P*p.
// ---------------------------------------------------------------------------
__global__ void prep_kernel(const float* __restrict__ f, const float* __restrict__ p,
                            unsigned short* __restrict__ fnorm,
                            unsigned short* __restrict__ Ppad,
                            unsigned short* __restrict__ ppad,
                            float* __restrict__ selfdot) {
    const int r = blockIdx.x * 4 + (threadIdx.x >> 6);
    const int lane = threadIdx.x & 63;
    const f32x2* frow2 = (const f32x2*)(f + (size_t)r * CC);
    f32x2 v[3];
    float ss = 0.f;
#pragma unroll
    for (int k = 0; k < 3; ++k) {
        v[k] = frow2[lane + 64 * k];
        ss = fmaf(v[k][0], v[k][0], fmaf(v[k][1], v[k][1], ss));
    }
#pragma unroll
    for (int off = 32; off; off >>= 1) ss += __shfl_xor(ss, off);
    const float rn = 1.0f / fmaxf(sqrtf(ss), 1e-12f);
    unsigned int* fnr32 = (unsigned int*)(fnorm + (size_t)r * CC);
#pragma unroll
    for (int k = 0; k < 3; ++k)
        fnr32[lane + 64 * k] = pk2(v[k][0] * rn, v[k][1] * rn);

    if (lane < 32) {
        float pv = 0.f, e = 0.f;
        if (lane < KK) { pv = p[(size_t)r * KK + lane]; e = expf(pv); }
        Ppad[(size_t)r * 32 + lane] = (lane < KK) ? f2bf(e)  : (unsigned short)0;
        ppad[(size_t)r * 32 + lane] = (lane < KK) ? f2bf(pv) : (unsigned short)0;
        float sd = e * pv;
#pragma unroll
        for (int off = 8; off; off >>= 1) sd += __shfl_xor(sd, off, 16);
        if (lane == 0) selfdot[r] = sd;
    }
}

// ---------------------------------------------------------------------------
// Kernel 2: 96x96 triangular pair tile (weight 2 off-diagonal), 4 waves 2x2,
// per-wave 48x48 = 3x3 frags of mfma_f32_16x16x32_bf16.
// Round-3 structure (2 buffers, 48KB LDS, 3 blocks/CU) with COUNTED vmcnt:
// issue stage(t+1), wait only stage(t) (vmcnt 6), keep next stage in flight
// across the barrier. Diagonal tiles stage both panels (uniform load count).
// Epilogue P/p tiles staged in the t=5 slot into buf0 (compute reads buf1).
// ---------------------------------------------------------------------------
__global__ __launch_bounds__(256, 2) void pair_kernel(
    const unsigned short* __restrict__ fnorm,
    const unsigned short* __restrict__ Ppad, const unsigned short* __restrict__ ppad,
    const float* __restrict__ selfdot, float* __restrict__ partials)
{
    __shared__ char lds[49152] __attribute__((aligned(16)));  // 2 bufs x 24576
    __shared__ float red[4][4];

    const int b = blockIdx.x;
    const int n = b / TT;
    int t = b % TT;
    int i = 0;
    while (t >= NT - i) { t -= NT - i; ++i; }
    const int j = i + t;
    const int s0 = i * TB, l0 = j * TB;
    const float wgt = (i == j) ? 1.f : 2.f;

    const int tid = threadIdx.x, lane = tid & 63, w = tid >> 6;
    const int wrow = w >> 1, wcol = w & 1;

    const unsigned short* fn = fnorm + (size_t)n * LL * CC;
    const int srow8 = lane >> 3, sch = lane & 7;   // f-staging geometry

    f32x4 acc[3][3] = {};

    // stage K-tile kt (64 elems = 128B per row) of both panels into buffer buf
    auto stageF = [&](int buf, int kt) {
        char* base = lds + buf * 24576;
#pragma unroll
        for (int q = 0; q < 3; ++q) {
            const int r0 = w * 24 + q * 8;
            const int row = r0 + srow8;
            const int swz = (sch ^ (row & 7)) << 4;
            gll16((const char*)(fn + (size_t)(s0 + row) * CC) + kt * 128 + swz,
                  base + r0 * 128);
            gll16((const char*)(fn + (size_t)(l0 + row) * CC) + kt * 128 + swz,
                  base + 12288 + r0 * 128);
        }
    };
    auto stagePP = [&]() {   // into buf0: P at [0,6144), p at [6144,12288)
        const char* Pb = (const char*)Ppad + (size_t)(n * LL + s0) * 64;
        const char* pb = (const char*)ppad + (size_t)(n * LL + l0) * 64;
        const int erow = lane >> 2, ech = lane & 3;
#pragma unroll
        for (int q3 = 0; q3 < 3; ++q3) {
            const int q = w * 3 + q3;                 // 0..11, wave-uniform
            const int qq = (q < 6) ? q : q - 6;
            const int row = qq * 16 + erow;
            const char* sb = (q < 6) ? Pb : pb;
            gll16(sb + row * 64 + ((ech ^ (row & 3)) << 4),
                  lds + ((q < 6) ? 0 : 6144) + qq * 1024);
        }
    };
    auto compute = [&](int buf) {
        const char* abase = lds + buf * 24576;
        const char* bbase = abase + 12288;
#pragma unroll
        for (int ks = 0; ks < 2; ++ks) {
            short8 a[3], bb[3];
#pragma unroll
            for (int im = 0; im < 3; ++im) {
                const int row = wrow * 48 + im * 16 + (lane & 15);
                a[im] = *(const short8*)(abase + row * 128
                         + (((ks * 4 + (lane >> 4)) ^ (row & 7)) << 4));
            }
#pragma unroll
            for (int jn = 0; jn < 3; ++jn) {
                const int row = wcol * 48 + jn * 16 + (lane & 15);
                bb[jn] = *(const short8*)(bbase + row * 128
                         + (((ks * 4 + (lane >> 4)) ^ (row & 7)) << 4));
            }
#pragma unroll
            for (int im = 0; im < 3; ++im)
#pragma unroll
                for (int jn = 0; jn < 3; ++jn)
                    acc[im][jn] = __builtin_amdgcn_mfma_f32_16x16x32_bf16(
                        a[im], bb[jn], acc[im][jn], 0, 0, 0);
        }
    };

    // 1-deep counted pipeline: 6 loads/wave/stage, never vmcnt(0) in the loop.
    stageF(0, 0);
#define K_ITER(TT_I, VMC) \
    { if (TT_I < 5) stageF((TT_I + 1) & 1, TT_I + 1); \
      else stagePP(); \
      asm volatile("s_waitcnt vmcnt(" #VMC ")" ::: "memory"); \
      asm volatile("s_barrier" ::: "memory"); \
      compute(TT_I & 1); \
      asm volatile("s_barrier" ::: "memory"); }
    K_ITER(0, 6)
    K_ITER(1, 6)
    K_ITER(2, 6)
    K_ITER(3, 6)
    K_ITER(4, 6)
    K_ITER(5, 3)
#undef K_ITER
    asm volatile("s_waitcnt vmcnt(0)" ::: "memory");   // PP tiles landed
    asm volatile("s_barrier" ::: "memory");

    // ---- epilogue: P tile at lds[0,6144), p tile at lds[6144,12288)
    short8 a2[3], b2[3];
#pragma unroll
    for (int im = 0; im < 3; ++im) {
        const int row = wrow * 48 + im * 16 + (lane & 15);
        a2[im] = *(const short8*)(lds + row * 64 + (((lane >> 4) ^ (row & 3)) << 4));
    }
#pragma unroll
    for (int jn = 0; jn < 3; ++jn) {
        const int row = wcol * 48 + jn * 16 + (lane & 15);
        b2[jn] = *(const short8*)(lds + 6144 + row * 64 + (((lane >> 4) ^ (row & 3)) << 4));
    }

    float pos = 0.f, neg = 0.f, npc = 0.f, nnc = 0.f;
#pragma unroll
    for (int im = 0; im < 3; ++im) {
        const f32x4 sd4 = *(const f32x4*)(selfdot + (size_t)n * LL + s0
                            + wrow * 48 + im * 16 + ((lane >> 4) << 2));
#pragma unroll
        for (int jn = 0; jn < 3; ++jn) {
            f32x4 z = {0.f, 0.f, 0.f, 0.f};
            f32x4 pdv = __builtin_amdgcn_mfma_f32_16x16x32_bf16(a2[im], b2[jn], z, 0, 0, 0);
#pragma unroll
            for (int r = 0; r < 4; ++r) {
                const float fc = acc[im][jn][r] - DINO_SHIFT;
                const float pc = sd4[r] - pdv[r];
                const float v = fc * pc;
                if (fc > 0.f)      { pos += v; npc += 1.f; }
                else if (fc < 0.f) { neg += v; nnc += 1.f; }
            }
        }
    }
    pos *= wgt; neg *= wgt; npc *= wgt; nnc *= wgt;

#pragma unroll
    for (int off = 32; off; off >>= 1) {
        pos += __shfl_xor(pos, off); neg += __shfl_xor(neg, off);
        npc += __shfl_xor(npc, off); nnc += __shfl_xor(nnc, off);
    }
    if (lane == 0) { red[w][0] = pos; red[w][1] = neg; red[w][2] = npc; red[w][3] = nnc; }
    __syncthreads();
    if (tid == 0) {
        partials[b * 4 + 0] = red[0][0] + red[1][0] + red[2][0] + red[3][0];
        partials[b * 4 + 1] = red[0][1] + red[1][1] + red[2][1] + red[3][1];
        partials[b * 4 + 2] = red[0][2] + red[1][2] + red[2][2] + red[3][2];
        partials[b * 4 + 3] = red[0][3] + red[1][3] + red[2][3] + red[3][3];
    }
}

// ---------------------------------------------------------------------------
// Kernel 3: deterministic final reduce
// ---------------------------------------------------------------------------
__global__ void final_kernel(const float* __restrict__ partials,
                             const float* __restrict__ pw,
                             const float* __restrict__ nw,
                             float* __restrict__ out) {
    __shared__ float red[4][4];
    const int tid = threadIdx.x;
    float pos = 0.f, neg = 0.f, np = 0.f, nn = 0.f;
    for (int i = tid; i < NBLK2; i += 256) {
        const f32x4 v = *(const f32x4*)(partials + i * 4);
        pos += v[0]; neg += v[1]; np += v[2]; nn += v[3];
    }
#pragma unroll
    for (int off = 32; off; off >>= 1) {
        pos += __shfl_xor(pos, off); neg += __shfl_xor(neg, off);
        np  += __shfl_xor(np, off);  nn  += __shfl_xor(nn, off);
    }
    const int w = tid >> 6, lane = tid & 63;
    if (lane == 0) { red[w][0] = pos; red[w][1] = neg; red[w][2] = np; red[w][3] = nn; }
    __syncthreads();
    if (tid == 0) {
        pos = red[0][0] + red[1][0] + red[2][0] + red[3][0];
        neg = red[0][1] + red[1][1] + red[2][1] + red[3][1];
        np  = red[0][2] + red[1][2] + red[2][2] + red[3][2];
        nn  = red[0][3] + red[1][3] + red[2][3] + red[3][3];
        out[0] = (pos / np) * pw[0] + (neg / nn) * nw[0];
    }
}

extern "C" void kernel_launch(void* const* d_in, const int* in_sizes, int n_in,
                              void* d_out, int out_size, void* d_ws, size_t ws_size,
                              hipStream_t stream) {
    const float* f  = (const float*)d_in[0];
    const float* p  = (const float*)d_in[1];
    const float* pw = (const float*)d_in[2];
    const float* nw = (const float*)d_in[3];
    float* out = (float*)d_out;

    // ws layout (16B-aligned): fnorm | Ppad | ppad | selfdot | partials
    unsigned short* fnorm = (unsigned short*)d_ws;                        // N*L*C bf16
    unsigned short* Ppad  = fnorm + (size_t)NN * LL * CC;                 // N*L*32
    unsigned short* ppad  = Ppad + (size_t)NN * LL * 32;                  // N*L*32
    float* selfdot  = (float*)(ppad + (size_t)NN * LL * 32);              // N*L
    float* partials = selfdot + (size_t)NN * LL;                          // NBLK2*4

    prep_kernel<<<(NN * LL) / 4, 256, 0, stream>>>(f, p, fnorm, Ppad, ppad, selfdot);
    pair_kernel<<<NBLK2, 256, 0, stream>>>(fnorm, Ppad, ppad, selfdot, partials);
    final_kernel<<<1, 256, 0, stream>>>(partials, pw, nw, out);
}

// Round 7
// 21.486 us; speedup vs baseline: 1.5425x; 1.1737x over previous
//
#include <hip/hip_runtime.h>
#include <math.h>
#include <stdint.h>

// Problem constants
#define NN 2
#define LL 2304          // 48*48
#define CC 384
#define KK 16
#define DINO_SHIFT 0.7f

// Tiling: 96x96 pair tiles over the (s<=l) triangle
#define NT 24                      // LL / 96
#define TB 96
#define TT ((NT * (NT + 1)) / 2)   // 300 tiles per batch
#define NBLK2 (NN * TT)            // 600 blocks

typedef __attribute__((ext_vector_type(8))) short short8;   // 8 bf16
typedef __attribute__((ext_vector_type(4))) float f32x4;
typedef __attribute__((ext_vector_type(2))) float f32x2;

#define AS_G __attribute__((address_space(1)))
#define AS_L __attribute__((address_space(3)))

__device__ __forceinline__ unsigned short f2bf(float x) {
    union { float f; uint32_t u; } v; v.f = x;
    uint32_t r = v.u + 0x7fffu + ((v.u >> 16) & 1u);   // RNE
    return (unsigned short)(r >> 16);
}

// fp32 -> fp8 e4m3fn (OCP), RNE, |x| <= 1 (no clamp/NaN path needed)
__device__ __forceinline__ unsigned int f2e4m3(float x) {
    unsigned int u = __float_as_uint(x);
    unsigned int s = (u >> 24) & 0x80u;
    unsigned int au = u & 0x7fffffffu;
    unsigned int code;
    if (au < 0x3C800000u) {            // |x| < 2^-6 -> subnormal (step 2^-9)
        code = (unsigned int)__builtin_rintf(__uint_as_float(au) * 512.0f);
    } else {
        unsigned int lsb = (au >> 20) & 1u;
        au += 0x7FFFFu + lsb;          // RNE into bit 20
        code = (au >> 20) - (120u << 3);
    }
    return s | code;
}
__device__ __forceinline__ unsigned short fp8pair(float a, float b) {
#if __has_builtin(__builtin_amdgcn_cvt_pk_fp8_f32)
    return (unsigned short)(__builtin_amdgcn_cvt_pk_fp8_f32(a, b, 0, false) & 0xffff);
#else
    return (unsigned short)(f2e4m3(a) | (f2e4m3(b) << 8));
#endif
}

__device__ __forceinline__ void gll16(const void* g, void* l) {
    // async global->LDS, 16B per lane; LDS dest = wave-uniform base + lane*16
    __builtin_amdgcn_global_load_lds((const AS_G unsigned int*)g,
                                     (AS_L unsigned int*)l, 16, 0, 0);
}

// ---------------------------------------------------------------------------
// Kernel 1: per row r: fnorm8 = fp8_e4m3(f_r / max(||f_r||,eps));
// Ppad/ppad = bf16 exp(p)/p padded to 32 (upper 16 zero); selfdot = sum P*p.
// ---------------------------------------------------------------------------
__global__ void prep_kernel(const float* __restrict__ f, const float* __restrict__ p,
                            unsigned char* __restrict__ fnorm8,
                            unsigned short* __restrict__ Ppad,
                            unsigned short* __restrict__ ppad,
                            float* __restrict__ selfdot) {
    const int r = blockIdx.x * 4 + (threadIdx.x >> 6);
    const int lane = threadIdx.x & 63;
    const f32x2* frow2 = (const f32x2*)(f + (size_t)r * CC);
    f32x2 v[3];
    float ss = 0.f;
#pragma unroll
    for (int k = 0; k < 3; ++k) {
        v[k] = frow2[lane + 64 * k];
        ss = fmaf(v[k][0], v[k][0], fmaf(v[k][1], v[k][1], ss));
    }
#pragma unroll
    for (int off = 32; off; off >>= 1) ss += __shfl_xor(ss, off);
    const float rn = 1.0f / fmaxf(sqrtf(ss), 1e-12f);
    unsigned short* fr = (unsigned short*)(fnorm8 + (size_t)r * CC);  // 192 fp8-pairs
#pragma unroll
    for (int k = 0; k < 3; ++k)
        fr[lane + 64 * k] = fp8pair(v[k][0] * rn, v[k][1] * rn);

    if (lane < 32) {
        float pv = 0.f, e = 0.f;
        if (lane < KK) { pv = p[(size_t)r * KK + lane]; e = expf(pv); }
        Ppad[(size_t)r * 32 + lane] = (lane < KK) ? f2bf(e)  : (unsigned short)0;
        ppad[(size_t)r * 32 + lane] = (lane < KK) ? f2bf(pv) : (unsigned short)0;
        float sd = e * pv;
#pragma unroll
        for (int off = 8; off; off >>= 1) sd += __shfl_xor(sd, off, 16);
        if (lane == 0) selfdot[r] = sd;
    }
}

// ---------------------------------------------------------------------------
// Kernel 2: 96x96 triangular pair tile (weight 2 off-diagonal), 4 waves 2x2,
// per-wave 48x48 = 3x3 frags of mfma_f32_16x16x32_fp8_fp8.
// fp8 staging: K-tile = 128 elems (128B/row), 3 K-iters, 2 buffers (48KB,
// 3 blocks/CU), counted vmcnt. Epilogue P/p (bf16) staged into buf1 in the
// last iter's slot; pdot via one zero-padded bf16 MFMA k-step.
// ---------------------------------------------------------------------------
__global__ __launch_bounds__(256, 2) void pair_kernel(
    const unsigned char* __restrict__ fnorm8,
    const unsigned short* __restrict__ Ppad, const unsigned short* __restrict__ ppad,
    const float* __restrict__ selfdot, float* __restrict__ partials)
{
    __shared__ char lds[49152] __attribute__((aligned(16)));  // 2 bufs x 24576
    __shared__ float red[4][4];

    const int b = blockIdx.x;
    const int n = b / TT;
    int t = b % TT;
    int i = 0;
    while (t >= NT - i) { t -= NT - i; ++i; }
    const int j = i + t;
    const int s0 = i * TB, l0 = j * TB;
    const float wgt = (i == j) ? 1.f : 2.f;

    const int tid = threadIdx.x, lane = tid & 63, w = tid >> 6;
    const int wrow = w >> 1, wcol = w & 1;

    const unsigned char* fn = fnorm8 + (size_t)n * LL * CC;
    const int srow8 = lane >> 3, sch = lane & 7;   // f-staging geometry

    f32x4 acc[3][3] = {};

    // stage K-tile kt (128 fp8 = 128B per row) of both panels into buffer buf
    auto stageF = [&](int buf, int kt) {
        char* base = lds + buf * 24576;
#pragma unroll
        for (int q = 0; q < 3; ++q) {
            const int r0 = w * 24 + q * 8;
            const int row = r0 + srow8;
            const int swz = (sch ^ (row & 7)) << 4;
            gll16(fn + (size_t)(s0 + row) * CC + kt * 128 + swz, base + r0 * 128);
            gll16(fn + (size_t)(l0 + row) * CC + kt * 128 + swz,
                  base + 12288 + r0 * 128);
        }
    };
    auto stagePP = [&]() {   // into buf1: P at [24576,30720), p at [30720,36864)
        const char* Pb = (const char*)Ppad + (size_t)(n * LL + s0) * 64;
        const char* pb = (const char*)ppad + (size_t)(n * LL + l0) * 64;
        const int erow = lane >> 2, ech = lane & 3;
#pragma unroll
        for (int q3 = 0; q3 < 3; ++q3) {
            const int q = w * 3 + q3;                 // 0..11, wave-uniform
            const int qq = (q < 6) ? q : q - 6;
            const int row = qq * 16 + erow;
            const char* sb = (q < 6) ? Pb : pb;
            gll16(sb + row * 64 + ((ech ^ (row & 3)) << 4),
                  lds + ((q < 6) ? 24576 : 30720) + qq * 1024);
        }
    };
    auto compute = [&](int buf) {
        const char* abase = lds + buf * 24576;
        const char* bbase = abase + 12288;
#pragma unroll
        for (int ks = 0; ks < 4; ++ks) {
            long a[3], bb[3];
            const int unit = ks * 2 + ((lane >> 5) & 1);
            const int w8 = ((lane >> 4) & 1) * 8;
#pragma unroll
            for (int im = 0; im < 3; ++im) {
                const int row = wrow * 48 + im * 16 + (lane & 15);
                a[im] = *(const long*)(abase + row * 128
                         + ((unit ^ (row & 7)) << 4) + w8);
            }
#pragma unroll
            for (int jn = 0; jn < 3; ++jn) {
                const int row = wcol * 48 + jn * 16 + (lane & 15);
                bb[jn] = *(const long*)(bbase + row * 128
                         + ((unit ^ (row & 7)) << 4) + w8);
            }
#pragma unroll
            for (int im = 0; im < 3; ++im)
#pragma unroll
                for (int jn = 0; jn < 3; ++jn)
                    acc[im][jn] = __builtin_amdgcn_mfma_f32_16x16x32_fp8_fp8(
                        a[im], bb[jn], acc[im][jn], 0, 0, 0);
        }
    };

    // 3-iter counted pipeline: 6 loads/wave/stage, never vmcnt(0) in the loop.
    stageF(0, 0);
    // it0
    stageF(1, 1);
    asm volatile("s_waitcnt vmcnt(6)" ::: "memory");
    asm volatile("s_barrier" ::: "memory");
    compute(0);
    asm volatile("s_barrier" ::: "memory");
    // it1
    stageF(0, 2);
    asm volatile("s_waitcnt vmcnt(6)" ::: "memory");
    asm volatile("s_barrier" ::: "memory");
    compute(1);
    asm volatile("s_barrier" ::: "memory");
    // it2
    stagePP();
    asm volatile("s_waitcnt vmcnt(3)" ::: "memory");
    asm volatile("s_barrier" ::: "memory");
    compute(0);
    asm volatile("s_barrier" ::: "memory");
    asm volatile("s_waitcnt vmcnt(0)" ::: "memory");   // PP tiles landed
    asm volatile("s_barrier" ::: "memory");

    // ---- epilogue: P tile at lds+24576, p tile at lds+30720 (bf16, 64B rows)
    short8 a2[3], b2[3];
#pragma unroll
    for (int im = 0; im < 3; ++im) {
        const int row = wrow * 48 + im * 16 + (lane & 15);
        a2[im] = *(const short8*)(lds + 24576 + row * 64
                  + (((lane >> 4) ^ (row & 3)) << 4));
    }
#pragma unroll
    for (int jn = 0; jn < 3; ++jn) {
        const int row = wcol * 48 + jn * 16 + (lane & 15);
        b2[jn] = *(const short8*)(lds + 30720 + row * 64
                  + (((lane >> 4) ^ (row & 3)) << 4));
    }

    float pos = 0.f, neg = 0.f, npc = 0.f, nnc = 0.f;
#pragma unroll
    for (int im = 0; im < 3; ++im) {
        const f32x4 sd4 = *(const f32x4*)(selfdot + (size_t)n * LL + s0
                            + wrow * 48 + im * 16 + ((lane >> 4) << 2));
#pragma unroll
        for (int jn = 0; jn < 3; ++jn) {
            f32x4 z = {0.f, 0.f, 0.f, 0.f};
            f32x4 pdv = __builtin_amdgcn_mfma_f32_16x16x32_bf16(a2[im], b2[jn], z, 0, 0, 0);
#pragma unroll
            for (int r = 0; r < 4; ++r) {
                const float fc = acc[im][jn][r] - DINO_SHIFT;
                const float pc = sd4[r] - pdv[r];
                const float v = fc * pc;
                if (fc > 0.f)      { pos += v; npc += 1.f; }
                else if (fc < 0.f) { neg += v; nnc += 1.f; }
            }
        }
    }
    pos *= wgt; neg *= wgt; npc *= wgt; nnc *= wgt;

#pragma unroll
    for (int off = 32; off; off >>= 1) {
        pos += __shfl_xor(pos, off); neg += __shfl_xor(neg, off);
        npc += __shfl_xor(npc, off); nnc += __shfl_xor(nnc, off);
    }
    if (lane == 0) { red[w][0] = pos; red[w][1] = neg; red[w][2] = npc; red[w][3] = nnc; }
    __syncthreads();
    if (tid == 0) {
        partials[b * 4 + 0] = red[0][0] + red[1][0] + red[2][0] + red[3][0];
        partials[b * 4 + 1] = red[0][1] + red[1][1] + red[2][1] + red[3][1];
        partials[b * 4 + 2] = red[0][2] + red[1][2] + red[2][2] + red[3][2];
        partials[b * 4 + 3] = red[0][3] + red[1][3] + red[2][3] + red[3][3];
    }
}

// ---------------------------------------------------------------------------
// Kernel 3: deterministic final reduce
// ---------------------------------------------------------------------------
__global__ void final_kernel(const float* __restrict__ partials,
                             const float* __restrict__ pw,
                             const float* __restrict__ nw,
                             float* __restrict__ out) {
    __shared__ float red[4][4];
    const int tid = threadIdx.x;
    float pos = 0.f, neg = 0.f, np = 0.f, nn = 0.f;
    for (int i = tid; i < NBLK2; i += 256) {
        const f32x4 v = *(const f32x4*)(partials + i * 4);
        pos += v[0]; neg += v[1]; np += v[2]; nn += v[3];
    }
#pragma unroll
    for (int off = 32; off; off >>= 1) {
        pos += __shfl_xor(pos, off); neg += __shfl_xor(neg, off);
        np  += __shfl_xor(np, off);  nn  += __shfl_xor(nn, off);
    }
    const int w = tid >> 6, lane = tid & 63;
    if (lane == 0) { red[w][0] = pos; red[w][1] = neg; red[w][2] = np; red[w][3] = nn; }
    __syncthreads();
    if (tid == 0) {
        pos = red[0][0] + red[1][0] + red[2][0] + red[3][0];
        neg = red[0][1] + red[1][1] + red[2][1] + red[3][1];
        np  = red[0][2] + red[1][2] + red[2][2] + red[3][2];
        nn  = red[0][3] + red[1][3] + red[2][3] + red[3][3];
        out[0] = (pos / np) * pw[0] + (neg / nn) * nw[0];
    }
}

extern "C" void kernel_launch(void* const* d_in, const int* in_sizes, int n_in,
                              void* d_out, int out_size, void* d_ws, size_t ws_size,
                              hipStream_t stream) {
    const float* f  = (const float*)d_in[0];
    const float* p  = (const float*)d_in[1];
    const float* pw = (const float*)d_in[2];
    const float* nw = (const float*)d_in[3];
    float* out = (float*)d_out;

    // ws layout (16B-aligned): fnorm8 | Ppad | ppad | selfdot | partials
    unsigned char* fnorm8 = (unsigned char*)d_ws;                         // N*L*C fp8
    unsigned short* Ppad  = (unsigned short*)(fnorm8 + (size_t)NN * LL * CC);
    unsigned short* ppad  = Ppad + (size_t)NN * LL * 32;                  // N*L*32
    float* selfdot  = (float*)(ppad + (size_t)NN * LL * 32);              // N*L
    float* partials = selfdot + (size_t)NN * LL;                          // NBLK2*4

    prep_kernel<<<(NN * LL) / 4, 256, 0, stream>>>(f, p, fnorm8, Ppad, ppad, selfdot);
    pair_kernel<<<NBLK2, 256, 0, stream>>>(fnorm8, Ppad, ppad, selfdot, partials);
    final_kernel<<<1, 256, 0, stream>>>(partials, pw, nw, out);
}